// Round 12
// baseline (48.449 us; speedup 1.0000x reference)
//
#include <hip/hip_runtime.h>
#include <math.h>

// WaveletLayerND: fused mexican-hat wavelet + grouped 3x3 conv (kernel 1),
// then 1x1 channel mix (kernel 2). B=4, O=I=32, H=W=128, fp32 throughout.
//
// Round 12: channel-granularity load pipeline on the tap-basis skeleton.
// r9/r11 showed extra ILP doesn't pay: the per-row lookahead-2 gives only
// ~64-128cy of cover vs ~200cy L1/L2 latency -> ~100cy exposed per row.
// Fix: double-buffer the whole 10-row x-strip (10 v2f per buffer). While
// computing channel c from bufX (~320+cy pure-VALU), issue all 10 loads of
// channel c+1 into bufY. Load latency is covered by a full channel of
// compute; only the first channel's load is exposed (once per wave).
// Buffers use static indices only (no runtime-indexed regs -> no scratch).
// Tap basis: TL/TC/TR[r] += w * psi, halo combine once in the epilogue.
// Natural VGPR, NO launch_bounds min-arg (r3/r4/r7: capping below natural
// footprint spills acc to scratch -> GBs of HBM traffic).

#define RSTRIP 8   // output rows per wave

typedef float v2f __attribute__((ext_vector_type(2)));

static __device__ __forceinline__ v2f vfma(float w, v2f a, v2f c) {
  return __builtin_elementwise_fma(a, (v2f){w, w}, c);
}
static __device__ __forceinline__ float bperm(int addr, float v) {
  return __int_as_float(__builtin_amdgcn_ds_bpermute(addr, __float_as_int(v)));
}
// psi((x-t)/s) scaled by m (= MH_C * row_validity):  m*(u-1)*exp(-u/2)
static __device__ __forceinline__ v2f psi2(v2f xv, float rs, float trs, float m) {
  const float NHL2E = -0.72134752044448170f; // -0.5 * log2(e)
  const v2f sx = __builtin_elementwise_fma(xv, (v2f){rs, rs}, (v2f){-trs, -trs});
  const v2f u  = sx * sx;
  v2f e;
  e.x = __builtin_amdgcn_exp2f(u.x * NHL2E);
  e.y = __builtin_amdgcn_exp2f(u.y * NHL2E);
  return __builtin_elementwise_fma(u, (v2f){m, m}, (v2f){-m, -m}) * e;
}

#define LDROW(base, r) (*(const v2f*)((base) + (size_t)(min(max((r), 0), 127)) * 128))

__global__ __launch_bounds__(256) void wavelet_grouped_conv(
    const float* __restrict__ x,      // (B, I, H, W)
    const float* __restrict__ scale,  // (O*I)
    const float* __restrict__ trans,  // (O*I)
    const float* __restrict__ wconv,  // (O, I, 3, 3)
    float* __restrict__ y,            // (B, O, H, W) workspace
    float mhc)
{
  const int tid   = threadIdx.x;
  const int lane  = tid & 63;
  const int iq    = tid >> 6;          // 0..3: which i-quarter this wave owns
  const int strip = blockIdx.x;        // 0..15
  const int o     = blockIdx.y;        // 0..31
  const int b     = blockIdx.z;        // 0..3
  const int r0    = strip * RSTRIP;
  const int c0    = lane << 1;         // this thread's two columns

  // bpermute byte-addresses: lane-1 and lane+1 (mod 64) — epilogue only
  const int a_up = ((lane + 63) & 63) << 2;
  const int a_dn = ((lane +  1) & 63) << 2;
  const bool lane0  = (lane == 0);
  const bool lane63 = (lane == 63);

  // row validity folded into the psi prefactor (0 == the conv's zero pad)
  const float mhc_m1 = (r0 > 0)       ? mhc : 0.f;   // input row r0-1
  const float mhc_p8 = (r0 + 8 < 128) ? mhc : 0.f;   // input row r0+8

  // per-tap accumulators: out[c] = TL[c-1] + TC[c] + TR[c+1] (combined at end)
  v2f TL[RSTRIP], TC[RSTRIP], TR[RSTRIP];
#pragma unroll
  for (int r = 0; r < RSTRIP; ++r) {
    TL[r] = (v2f){0.f, 0.f}; TC[r] = (v2f){0.f, 0.f}; TR[r] = (v2f){0.f, 0.f};
  }

  const float* xb = x + (size_t)b * 32 * 128 * 128;
  const int oibase = __builtin_amdgcn_readfirstlane(o * 32 + iq * 8);

  // channel-k x base (clamped to a legal channel for the tail prefetch)
#define CHBASE(k) (xb + (size_t)(min(iq * 8 + (k), 31)) * 128 * 128 + c0)

  // one channel: prefetch next channel's 10 rows into NBUF, then compute
  // this channel's psi+taps from BUF (pure register work).
#define CHANNEL(BUF, NBUF, K)                                               \
  {                                                                         \
    const int oi = oibase + (K);                                            \
    const float rs  = 1.0f / scale[oi];                                     \
    const float trs = trans[oi] * rs;                                       \
    const float* wp = wconv + oi * 9;                                       \
    const float w00 = wp[0], w01 = wp[1], w02 = wp[2];                      \
    const float w10 = wp[3], w11 = wp[4], w12 = wp[5];                      \
    const float w20 = wp[6], w21 = wp[7], w22 = wp[8];                      \
    const float* nb = CHBASE((K) + 1);                                      \
    _Pragma("unroll")                                                       \
    for (int k = 0; k < RSTRIP + 2; ++k) NBUF[k] = LDROW(nb, r0 + k - 1);   \
    _Pragma("unroll")                                                       \
    for (int j = 0; j < RSTRIP + 2; ++j) {                                  \
      const float mj = (j == 0) ? mhc_m1 : (j == RSTRIP + 1) ? mhc_p8 : mhc;\
      const v2f p = psi2(BUF[j], rs, trs, mj);                              \
      if (j <= RSTRIP - 1) {                                                \
        TL[j] = vfma(w00, p, TL[j]);                                        \
        TC[j] = vfma(w01, p, TC[j]);                                        \
        TR[j] = vfma(w02, p, TR[j]);                                        \
      }                                                                     \
      if (j >= 1 && j <= RSTRIP) {                                          \
        TL[j-1] = vfma(w10, p, TL[j-1]);                                    \
        TC[j-1] = vfma(w11, p, TC[j-1]);                                    \
        TR[j-1] = vfma(w12, p, TR[j-1]);                                    \
      }                                                                     \
      if (j >= 2) {                                                         \
        TL[j-2] = vfma(w20, p, TL[j-2]);                                    \
        TC[j-2] = vfma(w21, p, TC[j-2]);                                    \
        TR[j-2] = vfma(w22, p, TR[j-2]);                                    \
      }                                                                     \
    }                                                                       \
  }

  v2f bufA[RSTRIP + 2], bufB[RSTRIP + 2];
  {
    const float* b0 = CHBASE(0);
#pragma unroll
    for (int k = 0; k < RSTRIP + 2; ++k) bufA[k] = LDROW(b0, r0 + k - 1);
  }

#pragma unroll 1
  for (int ii = 0; ii < 4; ++ii) {
    CHANNEL(bufA, bufB, 2 * ii)       // compute ch 2ii, prefetch ch 2ii+1
    CHANNEL(bufB, bufA, 2 * ii + 1)   // compute ch 2ii+1, prefetch ch 2ii+2
  }
#undef CHANNEL
#undef CHBASE

  // horizontal combine: out[c0]   = TL[c0-1] + TC[c0]   + TR[c0+1]
  //                     out[c0+1] = TL[c0]   + TC[c0+1] + TR[c0+2]
  v2f acc[RSTRIP];
#pragma unroll
  for (int r = 0; r < RSTRIP; ++r) {
    float pl = bperm(a_up, TL[r].y);
    float pr = bperm(a_dn, TR[r].x);
    if (lane0)  pl = 0.f;
    if (lane63) pr = 0.f;
    v2f v;
    v.x = pl      + TC[r].x + TR[r].y;
    v.y = TL[r].x + TC[r].y + pr;
    acc[r] = v;
  }

  // reduce the four i-quarters through LDS (lane-major; b64 2-way is free)
  __shared__ v2f red[3][RSTRIP][64];   // 12 KB
  if (iq != 0) {
#pragma unroll
    for (int r = 0; r < RSTRIP; ++r) red[iq - 1][r][lane] = acc[r];
  }
  __syncthreads();
  if (iq == 0) {
    float* yb = y + (((size_t)b * 32 + o) * 128 + r0) * 128 + c0;
#pragma unroll
    for (int r = 0; r < RSTRIP; ++r) {
      const v2f v = acc[r] + red[0][r][lane] + red[1][r][lane] + red[2][r][lane];
      *(v2f*)(yb + (size_t)r * 128) = v;
    }
  }
}

__global__ __launch_bounds__(256) void mix1x1(
    const float* __restrict__ y,    // (B, O, H*W)
    const float* __restrict__ fw,   // (O_out, O_in)
    float* __restrict__ out)        // (B, O, H*W)
{
  const int px = blockIdx.x * 256 + threadIdx.x;  // 0..16383
  const int b  = blockIdx.y;
  const float* yb = y + (size_t)b * 32 * 16384 + px;
  float v[32];
#pragma unroll
  for (int o = 0; o < 32; ++o) v[o] = yb[(size_t)o * 16384];
  float* ob = out + (size_t)b * 32 * 16384 + px;
#pragma unroll
  for (int p = 0; p < 32; ++p) {
    float a = 0.f;
#pragma unroll
    for (int o = 0; o < 32; ++o) a = fmaf(fw[p * 32 + o], v[o], a);
    ob[(size_t)p * 16384] = a;
  }
}

extern "C" void kernel_launch(void* const* d_in, const int* in_sizes, int n_in,
                              void* d_out, int out_size, void* d_ws, size_t ws_size,
                              hipStream_t stream) {
  const float* x     = (const float*)d_in[0];
  const float* scale = (const float*)d_in[1];
  const float* trans = (const float*)d_in[2];
  const float* wconv = (const float*)d_in[3];
  const float* fw    = (const float*)d_in[4];
  float* out = (float*)d_out;
  float* y   = (float*)d_ws;   // 4*32*128*128 floats = 8.39 MB

  const float mhc = (float)(2.0 / (sqrt(3.0) * pow(M_PI, 0.25)));

  dim3 g1(128 / RSTRIP, 32, 4);  // (strips, o, b) = 2048 blocks x 256 thr
  wavelet_grouped_conv<<<g1, 256, 0, stream>>>(x, scale, trans, wconv, y, mhc);

  dim3 g2(16384 / 256, 4);       // (pixel tiles, b)
  mix1x1<<<g2, 256, 0, stream>>>(y, fw, out);
}

// Round 13
// 47.750 us; speedup vs baseline: 1.0146x; 1.0146x over previous
//
#include <hip/hip_runtime.h>
#include <math.h>

// WaveletLayerND: fused mexican-hat wavelet + grouped 3x3 conv (kernel 1),
// then 1x1 channel mix (kernel 2). B=4, O=I=32, H=W=128, fp32 throughout.
//
// Round 13: r12's channel-granularity double-buffer + sched_barrier(0) pins.
// r12 evidence: VGPR=68 (vs ~110 for a live dbuf) -> the register allocator
// SANK the prefetch loads to their uses, deleting the pipeline; ~200cy L2
// latency exposed per row-step (per-wave 22k cy vs 2.8k issue).
// Fix: __builtin_amdgcn_sched_barrier(0) between {prefetch next channel's
// 10 rows + params} and {compute current channel} — nothing may cross, so
// loads issue ~400cy (one channel of pure-register psi+taps) before use.
// Tap basis (r10): TL/TC/TR[r] += w * psi; halo combine once in epilogue.
// Natural VGPR; NO launch_bounds min-arg (r3/r4/r7: caps below natural
// footprint spill acc to scratch -> GBs of HBM traffic).

#define RSTRIP 8   // output rows per wave

typedef float v2f __attribute__((ext_vector_type(2)));

static __device__ __forceinline__ v2f vfma(float w, v2f a, v2f c) {
  return __builtin_elementwise_fma(a, (v2f){w, w}, c);
}
static __device__ __forceinline__ float bperm(int addr, float v) {
  return __int_as_float(__builtin_amdgcn_ds_bpermute(addr, __float_as_int(v)));
}
// psi((x-t)/s) scaled by m (= MH_C * row_validity):  m*(u-1)*exp(-u/2)
static __device__ __forceinline__ v2f psi2(v2f xv, float rs, float trs, float m) {
  const float NHL2E = -0.72134752044448170f; // -0.5 * log2(e)
  const v2f sx = __builtin_elementwise_fma(xv, (v2f){rs, rs}, (v2f){-trs, -trs});
  const v2f u  = sx * sx;
  v2f e;
  e.x = __builtin_amdgcn_exp2f(u.x * NHL2E);
  e.y = __builtin_amdgcn_exp2f(u.y * NHL2E);
  return __builtin_elementwise_fma(u, (v2f){m, m}, (v2f){-m, -m}) * e;
}

struct ChParams {
  float rs, trs;
  float w00, w01, w02, w10, w11, w12, w20, w21, w22;
};

#define LDROW(base, r) (*(const v2f*)((base) + (size_t)(min(max((r), 0), 127)) * 128))

__global__ __launch_bounds__(256) void wavelet_grouped_conv(
    const float* __restrict__ x,      // (B, I, H, W)
    const float* __restrict__ scale,  // (O*I)
    const float* __restrict__ trans,  // (O*I)
    const float* __restrict__ wconv,  // (O, I, 3, 3)
    float* __restrict__ y,            // (B, O, H, W) workspace
    float mhc)
{
  const int tid   = threadIdx.x;
  const int lane  = tid & 63;
  const int iq    = tid >> 6;          // 0..3: which i-quarter this wave owns
  const int strip = blockIdx.x;        // 0..15
  const int o     = blockIdx.y;        // 0..31
  const int b     = blockIdx.z;        // 0..3
  const int r0    = strip * RSTRIP;
  const int c0    = lane << 1;         // this thread's two columns

  // bpermute byte-addresses: lane-1 and lane+1 (mod 64) — epilogue only
  const int a_up = ((lane + 63) & 63) << 2;
  const int a_dn = ((lane +  1) & 63) << 2;
  const bool lane0  = (lane == 0);
  const bool lane63 = (lane == 63);

  // row validity folded into the psi prefactor (0 == the conv's zero pad)
  const float mhc_m1 = (r0 > 0)       ? mhc : 0.f;   // input row r0-1
  const float mhc_p8 = (r0 + 8 < 128) ? mhc : 0.f;   // input row r0+8

  // per-tap accumulators: out[c] = TL[c-1] + TC[c] + TR[c+1] (combined at end)
  v2f TL[RSTRIP], TC[RSTRIP], TR[RSTRIP];
#pragma unroll
  for (int r = 0; r < RSTRIP; ++r) {
    TL[r] = (v2f){0.f, 0.f}; TC[r] = (v2f){0.f, 0.f}; TR[r] = (v2f){0.f, 0.f};
  }

  const float* xb = x + (size_t)b * 32 * 128 * 128;
  const int oibase = __builtin_amdgcn_readfirstlane(o * 32 + iq * 8);

  // channel-k x base / param index (clamped to legal channel for tail dummy)
#define CHBASE(k) (xb + (size_t)(min(iq * 8 + (k), 31)) * 128 * 128 + c0)
#define CHOI(k)   (__builtin_amdgcn_readfirstlane(o * 32 + min(iq * 8 + (k), 31)))

#define LDPAR(P, K)                                              \
  {                                                              \
    const int oi_ = CHOI(K);                                     \
    (P).rs  = 1.0f / scale[oi_];                                 \
    (P).trs = trans[oi_] * (P).rs;                               \
    const float* wp_ = wconv + oi_ * 9;                          \
    (P).w00 = wp_[0]; (P).w01 = wp_[1]; (P).w02 = wp_[2];        \
    (P).w10 = wp_[3]; (P).w11 = wp_[4]; (P).w12 = wp_[5];        \
    (P).w20 = wp_[6]; (P).w21 = wp_[7]; (P).w22 = wp_[8];        \
  }

#define PREF(NBUF, K)                                            \
  {                                                              \
    const float* nb_ = CHBASE(K);                                \
    _Pragma("unroll")                                            \
    for (int k = 0; k < RSTRIP + 2; ++k)                         \
      NBUF[k] = LDROW(nb_, r0 + k - 1);                          \
  }

#define COMPUTE(BUF, P)                                                     \
  {                                                                         \
    _Pragma("unroll")                                                       \
    for (int j = 0; j < RSTRIP + 2; ++j) {                                  \
      const float mj = (j == 0) ? mhc_m1 : (j == RSTRIP + 1) ? mhc_p8 : mhc;\
      const v2f p = psi2(BUF[j], (P).rs, (P).trs, mj);                      \
      if (j <= RSTRIP - 1) {                                                \
        TL[j] = vfma((P).w00, p, TL[j]);                                    \
        TC[j] = vfma((P).w01, p, TC[j]);                                    \
        TR[j] = vfma((P).w02, p, TR[j]);                                    \
      }                                                                     \
      if (j >= 1 && j <= RSTRIP) {                                          \
        TL[j-1] = vfma((P).w10, p, TL[j-1]);                                \
        TC[j-1] = vfma((P).w11, p, TC[j-1]);                                \
        TR[j-1] = vfma((P).w12, p, TR[j-1]);                                \
      }                                                                     \
      if (j >= 2) {                                                         \
        TL[j-2] = vfma((P).w20, p, TL[j-2]);                                \
        TC[j-2] = vfma((P).w21, p, TC[j-2]);                                \
        TR[j-2] = vfma((P).w22, p, TR[j-2]);                                \
      }                                                                     \
    }                                                                       \
  }

  v2f bufA[RSTRIP + 2], bufB[RSTRIP + 2];
  ChParams pc, pn;
  PREF(bufA, 0)
  LDPAR(pc, 0)

#pragma unroll 1
  for (int ii = 0; ii < 4; ++ii) {
    // even channel: prefetch 2ii+1 into bufB/pn, then compute 2ii from bufA/pc
    PREF(bufB, 2 * ii + 1)
    LDPAR(pn, 2 * ii + 1)
    __builtin_amdgcn_sched_barrier(0);   // pin: loads above, compute below
    COMPUTE(bufA, pc)
    // odd channel: prefetch 2ii+2 into bufA/pc, then compute 2ii+1 from bufB/pn
    PREF(bufA, 2 * ii + 2)
    LDPAR(pc, 2 * ii + 2)
    __builtin_amdgcn_sched_barrier(0);
    COMPUTE(bufB, pn)
  }
#undef COMPUTE
#undef PREF
#undef LDPAR
#undef CHOI
#undef CHBASE

  // horizontal combine: out[c0]   = TL[c0-1] + TC[c0]   + TR[c0+1]
  //                     out[c0+1] = TL[c0]   + TC[c0+1] + TR[c0+2]
  v2f acc[RSTRIP];
#pragma unroll
  for (int r = 0; r < RSTRIP; ++r) {
    float pl = bperm(a_up, TL[r].y);
    float pr = bperm(a_dn, TR[r].x);
    if (lane0)  pl = 0.f;
    if (lane63) pr = 0.f;
    v2f v;
    v.x = pl      + TC[r].x + TR[r].y;
    v.y = TL[r].x + TC[r].y + pr;
    acc[r] = v;
  }

  // reduce the four i-quarters through LDS (lane-major; b64 2-way is free)
  __shared__ v2f red[3][RSTRIP][64];   // 12 KB
  if (iq != 0) {
#pragma unroll
    for (int r = 0; r < RSTRIP; ++r) red[iq - 1][r][lane] = acc[r];
  }
  __syncthreads();
  if (iq == 0) {
    float* yb = y + (((size_t)b * 32 + o) * 128 + r0) * 128 + c0;
#pragma unroll
    for (int r = 0; r < RSTRIP; ++r) {
      const v2f v = acc[r] + red[0][r][lane] + red[1][r][lane] + red[2][r][lane];
      *(v2f*)(yb + (size_t)r * 128) = v;
    }
  }
}

__global__ __launch_bounds__(256) void mix1x1(
    const float* __restrict__ y,    // (B, O, H*W)
    const float* __restrict__ fw,   // (O_out, O_in)
    float* __restrict__ out)        // (B, O, H*W)
{
  const int px = blockIdx.x * 256 + threadIdx.x;  // 0..16383
  const int b  = blockIdx.y;
  const float* yb = y + (size_t)b * 32 * 16384 + px;
  float v[32];
#pragma unroll
  for (int o = 0; o < 32; ++o) v[o] = yb[(size_t)o * 16384];
  float* ob = out + (size_t)b * 32 * 16384 + px;
#pragma unroll
  for (int p = 0; p < 32; ++p) {
    float a = 0.f;
#pragma unroll
    for (int o = 0; o < 32; ++o) a = fmaf(fw[p * 32 + o], v[o], a);
    ob[(size_t)p * 16384] = a;
  }
}

extern "C" void kernel_launch(void* const* d_in, const int* in_sizes, int n_in,
                              void* d_out, int out_size, void* d_ws, size_t ws_size,
                              hipStream_t stream) {
  const float* x     = (const float*)d_in[0];
  const float* scale = (const float*)d_in[1];
  const float* trans = (const float*)d_in[2];
  const float* wconv = (const float*)d_in[3];
  const float* fw    = (const float*)d_in[4];
  float* out = (float*)d_out;
  float* y   = (float*)d_ws;   // 4*32*128*128 floats = 8.39 MB

  const float mhc = (float)(2.0 / (sqrt(3.0) * pow(M_PI, 0.25)));

  dim3 g1(128 / RSTRIP, 32, 4);  // (strips, o, b) = 2048 blocks x 256 thr
  wavelet_grouped_conv<<<g1, 256, 0, stream>>>(x, scale, trans, wconv, y, mhc);

  dim3 g2(16384 / 256, 4);       // (pixel tiles, b)
  mix1x1<<<g2, 256, 0, stream>>>(y, fw, out);
}

// Round 14
// 46.288 us; speedup vs baseline: 1.0467x; 1.0316x over previous
//
#include <hip/hip_runtime.h>
#include <math.h>

// WaveletLayerND: fused mexican-hat wavelet + grouped 3x3 conv (kernel 1),
// then 1x1 channel mix (kernel 2). B=4, O=I=32, H=W=128, fp32 throughout.
//
// Round 14: LDS staging via global_load_lds (the un-sinkable prefetch).
// r9-r13 evidence: every register-level prefetch (ILP, dbuf, sched_barrier)
// is rewritten by the allocator into load->use (r12: VGPR=68 vs ~110 for a
// live dbuf) -> ~200-300cy exposed VMEM latency per row-step, kernel stuck
// at ~40us vs ~8us VALU floor. global_load_lds has NO VGPR destination, so
// it cannot be sunk; latency is structurally hidden by the 2-phase
// stage-ahead loop (stage chunk c+1 -> compute chunk c -> vmcnt(0) barrier).
// Block = (strip, o-group-of-8, b): 1024 thr = 16 waves = 8 o x 2 i-halves,
// x strip staged ONCE and shared by all 8 o (4x less VMEM than r13).
// Grid 16x4x4 = 256 blocks = exactly 1/CU, 16 waves/CU resident.
// Compute: r10 tap-basis (TL/TC/TR += w*psi; halo = 2 bperm/row, epilogue).
// LDS: 2 x 20KB chunk dbuf (4 ch x 10 rows x 512B); i-half reduce overlays
// the stage area after the final barrier. 40KB total.
// Natural VGPR; NO launch_bounds min-arg (r3/r4/r7: caps below natural
// footprint spill acc to scratch -> GBs of HBM traffic).

#define RSTRIP 8   // output rows per strip

typedef float v2f __attribute__((ext_vector_type(2)));

static __device__ __forceinline__ v2f vfma(float w, v2f a, v2f c) {
  return __builtin_elementwise_fma(a, (v2f){w, w}, c);
}
static __device__ __forceinline__ float bperm(int addr, float v) {
  return __int_as_float(__builtin_amdgcn_ds_bpermute(addr, __float_as_int(v)));
}
// psi((x-t)/s) scaled by m (= MH_C * row_validity):  m*(u-1)*exp(-u/2)
static __device__ __forceinline__ v2f psi2(v2f xv, float rs, float trs, float m) {
  const float NHL2E = -0.72134752044448170f; // -0.5 * log2(e)
  const v2f sx = __builtin_elementwise_fma(xv, (v2f){rs, rs}, (v2f){-trs, -trs});
  const v2f u  = sx * sx;
  v2f e;
  e.x = __builtin_amdgcn_exp2f(u.x * NHL2E);
  e.y = __builtin_amdgcn_exp2f(u.y * NHL2E);
  return __builtin_elementwise_fma(u, (v2f){m, m}, (v2f){-m, -m}) * e;
}
// async global->LDS, 16B per lane. LDS dest is wave-uniform base + lane*16
// (m104 caveat); global src is per-lane.
static __device__ __forceinline__ void gload_lds16(const float* g, float* l) {
  __builtin_amdgcn_global_load_lds(
      (const __attribute__((address_space(1))) void*)g,
      (__attribute__((address_space(3))) void*)l, 16, 0, 0);
}

__global__ __launch_bounds__(1024) void wavelet_grouped_conv(
    const float* __restrict__ x,      // (B, I, H, W)
    const float* __restrict__ scale,  // (O*I)
    const float* __restrict__ trans,  // (O*I)
    const float* __restrict__ wconv,  // (O, I, 3, 3)
    float* __restrict__ y,            // (B, O, H, W) workspace
    float mhc)
{
  const int tid   = threadIdx.x;
  const int lane  = tid & 63;
  const int w     = tid >> 6;          // 0..15
  const int o_idx = w & 7;             // which o of the 8 in this block
  const int ihalf = w >> 3;            // 0: even ch-pair of chunk, 1: odd
  const int strip = blockIdx.x;        // 0..15
  const int og    = blockIdx.y;        // 0..3
  const int b     = blockIdx.z;        // 0..3
  const int o     = og * 8 + o_idx;
  const int r0    = strip * RSTRIP;
  const int c0    = lane << 1;         // this thread's two columns

  // bpermute byte-addresses: lane-1 / lane+1 (mod 64) — epilogue only
  const int a_up = ((lane + 63) & 63) << 2;
  const int a_dn = ((lane +  1) & 63) << 2;
  const bool lane0  = (lane == 0);
  const bool lane63 = (lane == 63);

  // row validity folded into the psi prefactor (0 == the conv's zero pad)
  const float mhc_m1 = (r0 > 0)       ? mhc : 0.f;   // input row r0-1
  const float mhc_p8 = (r0 + 8 < 128) ? mhc : 0.f;   // input row r0+8

  // per-tap accumulators: out[c] = TL[c-1] + TC[c] + TR[c+1] (combined at end)
  v2f TL[RSTRIP], TC[RSTRIP], TR[RSTRIP];
#pragma unroll
  for (int r = 0; r < RSTRIP; ++r) {
    TL[r] = (v2f){0.f, 0.f}; TC[r] = (v2f){0.f, 0.f}; TR[r] = (v2f){0.f, 0.f};
  }

  const float* xb = x + (size_t)b * 32 * 128 * 128;

  // LDS: double-buffered 4-channel chunk (4 ch x 10 rows x 128 f = 5120 f)
  __shared__ float stage[2][5120];     // 40 KB

  // Stage chunk c (channels 4c..4c+3) into buf. 20 slices of 1024B; slice s:
  // ch = s/5, rowpair = s%5; lane: row = 2*rp + (lane>>5), col4 = lane&31.
  // LDS layout: ((ch*10 + row)*128 + col4*4) floats == slice-linear s*256 + lane*4.
#define STAGE(bufp, c)                                                  \
  {                                                                     \
    _Pragma("unroll")                                                   \
    for (int t = 0; t < 2; ++t) {                                       \
      const int s = w + t * 16;                                         \
      if (s < 20) {                                                     \
        const int ch = s / 5, rp = s % 5;                               \
        const int row = 2 * rp + (lane >> 5);                           \
        const int ir  = min(max(r0 + row - 1, 0), 127);                 \
        const float* g = xb + (size_t)((c) * 4 + ch) * 16384            \
                            + ir * 128 + (lane & 31) * 4;               \
        gload_lds16(g, (bufp) + s * 256);                               \
      }                                                                 \
    }                                                                   \
  }

  // Compute this wave's 2 channels of chunk c from LDS (tap basis).
#define COMPUTE(bufp, c)                                                    \
  {                                                                         \
    _Pragma("unroll")                                                       \
    for (int cl = 0; cl < 2; ++cl) {                                        \
      const int chl = 2 * ihalf + cl;                                       \
      const int oi = __builtin_amdgcn_readfirstlane(o * 32 + (c) * 4 + chl);\
      const float rs  = 1.0f / scale[oi];                                   \
      const float trs = trans[oi] * rs;                                     \
      const float* wp = wconv + oi * 9;                                     \
      const float w00 = wp[0], w01 = wp[1], w02 = wp[2];                    \
      const float w10 = wp[3], w11 = wp[4], w12 = wp[5];                    \
      const float w20 = wp[6], w21 = wp[7], w22 = wp[8];                    \
      const float* xs = (bufp) + chl * 1280 + c0;                           \
      _Pragma("unroll")                                                     \
      for (int j = 0; j < RSTRIP + 2; ++j) {                                \
        const float mj = (j == 0) ? mhc_m1 : (j == RSTRIP + 1) ? mhc_p8 : mhc;\
        const v2f p = psi2(*(const v2f*)(xs + j * 128), rs, trs, mj);       \
        if (j <= RSTRIP - 1) {                                              \
          TL[j] = vfma(w00, p, TL[j]);                                      \
          TC[j] = vfma(w01, p, TC[j]);                                      \
          TR[j] = vfma(w02, p, TR[j]);                                      \
        }                                                                   \
        if (j >= 1 && j <= RSTRIP) {                                        \
          TL[j-1] = vfma(w10, p, TL[j-1]);                                  \
          TC[j-1] = vfma(w11, p, TC[j-1]);                                  \
          TR[j-1] = vfma(w12, p, TR[j-1]);                                  \
        }                                                                   \
        if (j >= 2) {                                                       \
          TL[j-2] = vfma(w20, p, TL[j-2]);                                  \
          TC[j-2] = vfma(w21, p, TC[j-2]);                                  \
          TR[j-2] = vfma(w22, p, TR[j-2]);                                  \
        }                                                                   \
      }                                                                     \
    }                                                                       \
  }

  STAGE(stage[0], 0)
  asm volatile("s_waitcnt vmcnt(0)" ::: "memory");
  __syncthreads();

#pragma unroll 1
  for (int c = 0; c < 8; ++c) {
    if (c < 7) STAGE(stage[(c + 1) & 1], c + 1)   // issue-ahead (fire-and-forget)
    COMPUTE(stage[c & 1], c)
    asm volatile("s_waitcnt vmcnt(0)" ::: "memory");
    __syncthreads();
  }
#undef COMPUTE
#undef STAGE

  // horizontal combine: out[c0]   = TL[c0-1] + TC[c0]   + TR[c0+1]
  //                     out[c0+1] = TL[c0]   + TC[c0+1] + TR[c0+2]
  v2f acc[RSTRIP];
#pragma unroll
  for (int r = 0; r < RSTRIP; ++r) {
    float pl = bperm(a_up, TL[r].y);
    float pr = bperm(a_dn, TR[r].x);
    if (lane0)  pl = 0.f;
    if (lane63) pr = 0.f;
    v2f v;
    v.x = pl      + TC[r].x + TR[r].y;
    v.y = TL[r].x + TC[r].y + pr;
    acc[r] = v;
  }

  // i-half reduce through LDS, overlaying the stage area (all staging/compute
  // finished at the last barrier). 8 o x 8 r x 64 lanes x v2f = 32 KB.
  float* red = &stage[0][0];
  if (ihalf == 1) {
#pragma unroll
    for (int r = 0; r < RSTRIP; ++r)
      *(v2f*)(red + ((o_idx * RSTRIP + r) * 64 + lane) * 2) = acc[r];
  }
  __syncthreads();
  if (ihalf == 0) {
    float* yb = y + (((size_t)b * 32 + o) * 128 + r0) * 128 + c0;
#pragma unroll
    for (int r = 0; r < RSTRIP; ++r) {
      const v2f v = acc[r] + *(const v2f*)(red + ((o_idx * RSTRIP + r) * 64 + lane) * 2);
      *(v2f*)(yb + (size_t)r * 128) = v;
    }
  }
}

__global__ __launch_bounds__(256) void mix1x1(
    const float* __restrict__ y,    // (B, O, H*W)
    const float* __restrict__ fw,   // (O_out, O_in)
    float* __restrict__ out)        // (B, O, H*W)
{
  const int px = blockIdx.x * 256 + threadIdx.x;  // 0..16383
  const int b  = blockIdx.y;
  const float* yb = y + (size_t)b * 32 * 16384 + px;
  float v[32];
#pragma unroll
  for (int o = 0; o < 32; ++o) v[o] = yb[(size_t)o * 16384];
  float* ob = out + (size_t)b * 32 * 16384 + px;
#pragma unroll
  for (int p = 0; p < 32; ++p) {
    float a = 0.f;
#pragma unroll
    for (int o = 0; o < 32; ++o) a = fmaf(fw[p * 32 + o], v[o], a);
    ob[(size_t)p * 16384] = a;
  }
}

extern "C" void kernel_launch(void* const* d_in, const int* in_sizes, int n_in,
                              void* d_out, int out_size, void* d_ws, size_t ws_size,
                              hipStream_t stream) {
  const float* x     = (const float*)d_in[0];
  const float* scale = (const float*)d_in[1];
  const float* trans = (const float*)d_in[2];
  const float* wconv = (const float*)d_in[3];
  const float* fw    = (const float*)d_in[4];
  float* out = (float*)d_out;
  float* y   = (float*)d_ws;   // 4*32*128*128 floats = 8.39 MB

  const float mhc = (float)(2.0 / (sqrt(3.0) * pow(M_PI, 0.25)));

  dim3 g1(16, 4, 4);             // (strip, o-group-of-8, b) = 256 blocks x 1024 thr
  wavelet_grouped_conv<<<g1, 1024, 0, stream>>>(x, scale, trans, wconv, y, mhc);

  dim3 g2(16384 / 256, 4);       // (pixel tiles, b)
  mix1x1<<<g2, 256, 0, stream>>>(y, fw, out);
}